// Round 16
// baseline (4151.963 us; speedup 1.0000x reference)
//
#include <hip/hip_runtime.h>
#include <hip/hip_bf16.h>

// ---------------------------------------------------------------------------
// CharRNN: emb -> 4x conv1d(SAME) -> concat -> GRU(256) last state.
//
// xw[b,t,:] = beff + sum_{d=0..4} EmbW[d][X[b,t+d-2]][:]   (f32 tables in ws)
//
// R16: R15's local path failed AFTER passing its self-test. Mechanism:
// __hip_atomic_fetch_or(p,0) is an IDEMPOTENT RMW -> LLVM converts it to an
// atomic LOAD; at workgroup scope that load may be served from stale L1.
// Self-test false-positived on first-touch (L1 miss -> fresh L2 line);
// steady-state re-reads went stale. Fix: INLINE-ASM hardware atomics
// (global_atomic_or sc0 / global_atomic_swap) -- not convertible, and HW
// atomics always execute at L2 (never L1). Two-phase self-test (must observe
// an UPDATE, not just first value) gates the local path; fallback = R14
// agent protocol byte-identical (proven PASS).
// ---------------------------------------------------------------------------

typedef float f32x4 __attribute__((ext_vector_type(4)));
typedef short s16x8 __attribute__((ext_vector_type(8)));
typedef int   i32x4 __attribute__((ext_vector_type(4)));
typedef unsigned short u16;
typedef unsigned int   u32;
typedef unsigned long long u64;

// ws byte offsets
#define OFF_WC    0u         // f32  [5][64][768]
#define OFF_EMBW  983040u    // f32  [5][128][768]
#define OFF_BEFF  2949120u   // f32  [768]
#define OFF_WHP   2952192u   // bf16 [768][256] (Wh^T)
#define OFF_MODE  3345408u   // int
#define OFF_HGP   3345472u   // u32 [2][8][16][256]  (par, group, row, hcol)
#define OFF_CTL   3607616u   // tickets line0; test[g]@128*(1+g); vcnt@128*9; vcnt2@128*10
#define WS_NEED   3609024u

#define MAGIC1 0xA5A5A5A5u
#define MAGIC2 0x5A5A5A5Au

__device__ __forceinline__ float bf2f(u16 v){
  unsigned u = ((unsigned)v) << 16; return __builtin_bit_cast(float, u);
}
__device__ __forceinline__ u16 f2bf(float f){
  unsigned u = __builtin_bit_cast(unsigned, f);
  unsigned r = u + 0x7FFFu + ((u >> 16) & 1u);
  return (u16)(r >> 16);
}
__device__ __forceinline__ float ldv(const void* p, int i, int m){
  return m ? ((const float*)p)[i] : bf2f(((const u16*)p)[i]);
}
// HW atomic read (executes at L2; immune to idempotent-RMW->load transform)
__device__ __forceinline__ u32 atom_read(u32* p){
  u32 rv, z = 0u;
  asm volatile("global_atomic_or %0, %1, %2, off sc0"
               : "=&v"(rv) : "v"(p), "v"(z) : "memory");
  asm volatile("s_waitcnt vmcnt(0)" : "+v"(rv) :: "memory");
  return rv;
}
// HW atomic publish (swap, result discarded; stays a real atomic at L2)
__device__ __forceinline__ void atom_pub(u32* p, u32 v){
  asm volatile("global_atomic_swap %0, %1, off" :: "v"(p), "v"(v) : "memory");
}

// ---- init: zero h parity planes + control area ----
__global__ void k_init(char* ws){
  int idx = blockIdx.x*256 + threadIdx.x;
  u32* hg = (u32*)(ws + OFF_HGP);
  if (idx < 65536) hg[idx] = 0u;
  if (idx < 352) ((u32*)(ws + OFF_CTL))[idx] = 0u;
}

// ---- probe: detect storage dtype of emb_table ----
__global__ void k_probe(const void* __restrict__ emb, char* ws){
  const u16* w = (const u16*)emb;
  const int ln = threadIdx.x;
  bool bad = false;
  for (int j = 0; j < 8; ++j){
    u16 v = w[ln*8 + j];
    if (((v >> 7) & 0xFF) >= 0x86) bad = true;
  }
  unsigned long long m = __ballot(bad);
  if (ln == 0) *(int*)(ws + OFF_MODE) = (__popcll(m) > 4) ? 1 : 0;
}

// ---- Wc[d][e][j] = sum_br sum_c w_br[d-2+pad][e][c] * Wx[off_br+c][j] ----
__global__ void k_wc(const void* __restrict__ w2, const void* __restrict__ w3,
                     const void* __restrict__ w4, const void* __restrict__ w5,
                     const void* __restrict__ Wx, char* ws){
  const int md = *(const int*)(ws + OFF_MODE);
  const int d = blockIdx.x >> 6;
  const int e = blockIdx.x & 63;
  const int j0 = threadIdx.x;
  const void* wv[4] = {w2,w3,w4,w5};
  const int Kk[4] = {2,3,4,5}, pd[4] = {0,1,1,2};
  float a0=0.f, a1=0.f, a2=0.f;
  for (int br=0; br<4; ++br){
    int k = d - 2 + pd[br];
    if (k < 0 || k >= Kk[br]) continue;
    const int wbase  = (k*64 + e)*128;
    const int wxbase = (br*128)*768;
    for (int c=0; c<128; ++c){
      float wcv = ldv(wv[br], wbase + c, md);
      a0 += wcv * ldv(Wx, wxbase + c*768 + j0      , md);
      a1 += wcv * ldv(Wx, wxbase + c*768 + j0 + 256, md);
      a2 += wcv * ldv(Wx, wxbase + c*768 + j0 + 512, md);
    }
  }
  float* o = (float*)(ws + OFF_WC) + (d*64 + e)*768;
  o[j0] = a0; o[j0+256] = a1; o[j0+512] = a2;
}

// ---- beff[j] = b_in[j] + sum_br sum_c b_br[c]*Wx[off+c][j] ----
__global__ void k_beff(const void* __restrict__ b2, const void* __restrict__ b3,
                       const void* __restrict__ b4, const void* __restrict__ b5,
                       const void* __restrict__ Wx, const void* __restrict__ bin,
                       char* ws){
  const int md = *(const int*)(ws + OFF_MODE);
  int j = blockIdx.x*256 + threadIdx.x;
  if (j >= 768) return;
  const void* bv[4] = {b2,b3,b4,b5};
  float acc = ldv(bin, j, md);
  for (int br=0; br<4; ++br)
    for (int c=0; c<128; ++c)
      acc += ldv(bv[br], c, md) * ldv(Wx, (br*128 + c)*768 + j, md);
  ((float*)(ws + OFF_BEFF))[j] = acc;
}

// ---- EmbW[d][ch][j] = sum_e emb[ch][e] * Wc[d][e][j]  (f32 out) ----
__global__ void k_embw(const void* __restrict__ emb, char* ws){
  const int md = *(const int*)(ws + OFF_MODE);
  const int d = blockIdx.x >> 7, ch = blockIdx.x & 127;
  const float* wc = (const float*)(ws + OFF_WC) + d*64*768;
  float* ew = (float*)(ws + OFF_EMBW) + (size_t)(d*128 + ch)*768;
  const int j0 = threadIdx.x;
  float a0=0.f, a1=0.f, a2=0.f;
  for (int e=0; e<64; ++e){
    float ev = ldv(emb, ch*64 + e, md);
    a0 += ev*wc[e*768 + j0      ];
    a1 += ev*wc[e*768 + j0 + 256];
    a2 += ev*wc[e*768 + j0 + 512];
  }
  ew[j0] = a0; ew[j0+256] = a1; ew[j0+512] = a2;
}

// ---- whp[j][k] = Wh[k][j]  (bf16 out) ----
__global__ void k_whp(const void* __restrict__ Wh, char* ws){
  const int md = *(const int*)(ws + OFF_MODE);
  const int j = blockIdx.x, k = threadIdx.x;
  ((u16*)(ws + OFF_WHP))[j*256 + k] = f2bf(ldv(Wh, k*768 + j, md));
}

// ---- GRU: 32 blocks = 8 groups x 4 slices; 512 thr / 8 waves ----
__launch_bounds__(512, 1)
__global__ void k_gru(const int* __restrict__ X, const void* __restrict__ brec,
                      char* __restrict__ ws, void* __restrict__ outv){
  const int tid = threadIdx.x;
  const int w   = tid >> 6, ln = tid & 63;
  const int l15 = ln & 15, l4 = ln >> 4;

  const int md = *(const int*)(ws + OFF_MODE);
  const float* embw = (const float*)(ws + OFF_EMBW);
  const float* beff = (const float*)(ws + OFF_BEFF);
  const u16*   whp  = (const u16*)(ws + OFF_WHP);
  u32* hgp = (u32*)(ws + OFF_HGP);

  __shared__ int   Xs[16*512];           // 32 KB
  __shared__ float xwlds[2][16][196];    // 25 KB
  __shared__ float hwp[2][16][196];      // 25 KB
  __shared__ u16   hstage[2][16][272];   // 17 KB
  __shared__ int   blkinfo[3];           // g, r, local

  // ---- XCD self-organization + 2-phase local self-test (one thread) ----
  if (tid == 0){
    int xcc = 0;
    asm volatile("s_getreg_b32 %0, hwreg(HW_REG_XCC_ID)" : "=s"(xcc));
    xcc &= 7;
    int* ctl = (int*)(ws + OFF_CTL);          // tickets [0..7], total [8]
    int rank = __hip_atomic_fetch_add(&ctl[xcc], 1, __ATOMIC_RELAXED, __HIP_MEMORY_SCOPE_AGENT);
    __hip_atomic_fetch_add(&ctl[8], 1, __ATOMIC_RELEASE, __HIP_MEMORY_SCOPE_AGENT);
    int guard = 0;
    while (__hip_atomic_load(&ctl[8], __ATOMIC_ACQUIRE, __HIP_MEMORY_SCOPE_AGENT) < 32){
      if (++guard > (1<<24)) break;
    }
    int cnt[8];
    #pragma unroll
    for (int x=0; x<8; ++x)
      cnt[x] = __hip_atomic_load(&ctl[x], __ATOMIC_RELAXED, __HIP_MEMORY_SCOPE_AGENT);
    int g_, r_;
    if (rank < 4){ g_ = xcc; r_ = rank; }
    else {
      int oidx = rank - 4;
      for (int x=0; x<xcc; ++x){ int e = cnt[x]-4; if (e>0) oidx += e; }
      g_ = 0; r_ = 0; int k = 0;
      for (int x=0; x<8; ++x){
        int have = cnt[x] < 4 ? cnt[x] : 4;
        for (int rr=have; rr<4; ++rr){ if (k == oidx){ g_ = x; r_ = rr; } ++k; }
      }
    }
    int local_final = 0;
    if (cnt[g_] >= 4 && rank < 4){
      u32* tw   = (u32*)(ws + OFF_CTL + 128u*(1u + (unsigned)g_));
      int* vcnt  = (int*)(ws + OFF_CTL + 128u*9u);
      int* vcnt2 = (int*)(ws + OFF_CTL + 128u*10u);
      // phase 1: observe MAGIC1 via HW atomic read
      if (r_ == 0) atom_pub(tw, MAGIC1);
      int saw1 = 0;
      for (int t = 0; t < (1<<14); ++t){
        if (atom_read(tw) == MAGIC1){ saw1 = 1; break; }
      }
      // ack, then rank0 publishes the UPDATE (MAGIC2)
      __hip_atomic_fetch_add(&vcnt2[g_], 1, __ATOMIC_RELEASE, __HIP_MEMORY_SCOPE_AGENT);
      if (r_ == 0){
        guard = 0;
        while (__hip_atomic_load(&vcnt2[g_], __ATOMIC_ACQUIRE, __HIP_MEMORY_SCOPE_AGENT) < 4){
          if (++guard > (1<<22)) break;
        }
        atom_pub(tw, MAGIC2);
      }
      // phase 2: must observe the update (stale caches fail here)
      int saw2 = 0;
      for (int t = 0; t < (1<<14); ++t){
        if (atom_read(tw) == MAGIC2){ saw2 = 1; break; }
      }
      __hip_atomic_fetch_add(&vcnt[g_], (saw1 && saw2) ? 1 : 16, __ATOMIC_RELEASE, __HIP_MEMORY_SCOPE_AGENT);
      int vg = 0; guard = 0;
      for (;;){
        vg = __hip_atomic_load(&vcnt[g_], __ATOMIC_ACQUIRE, __HIP_MEMORY_SCOPE_AGENT);
        if (vg >= 4 || ++guard > (1<<22)) break;
      }
      local_final = (vg == 4) ? 1 : 0;
    }
    blkinfo[0] = g_; blkinfo[1] = r_; blkinfo[2] = local_final;
  }
  __syncthreads();
  const int g = blkinfo[0], r = blkinfo[1];
  const bool localg = blkinfo[2] != 0;

  for (int i = tid; i < 2048; i += 512)
    ((i32x4*)Xs)[i] = ((const i32x4*)(X + g*16*512))[i];

  // persistent Wh B-frags: wave w -> subtile w&3, K-half w>>2
  const int qs = (w >> 2) * 4;
  s16x8 Bf[3][4];
  #pragma unroll
  for (int gg=0; gg<3; ++gg){
    const int col = gg*256 + r*64 + (w&3)*16 + l15;
    #pragma unroll
    for (int qi=0; qi<4; ++qi)
      Bf[gg][qi] = *(const s16x8*)(whp + col*256 + (qs+qi)*32 + l4*8);
  }

  // gates: thread -> h-col hc = r*64+(tid&63), rows tr, tr+8
  const int c63 = tid & 63;
  const int tr  = (tid >> 6) & 7;
  const int hc  = r*64 + c63;
  const float br0 = ldv(brec,       hc, md);
  const float br1 = ldv(brec, 256 + hc, md);
  const float br2 = ldv(brec, 512 + hc, md);

  // gather: chunk ids cid1 = tid, cid2 = tid+512 (tid<256 only)
  const int row1 = tid / 48,      rem1 = tid % 48;
  const int gg1  = rem1 / 16,     cc1  = rem1 % 16;
  const int cid2 = tid + 512;
  const int row2 = cid2 / 48,     rem2 = cid2 % 48;
  const int gg2  = rem2 / 16,     cc2  = rem2 % 16;
  const bool two = (tid < 256);
  const int gcol1 = gg1*256 + r*64 + cc1*4;
  const int gcol2 = gg2*256 + r*64 + cc2*4;
  const f32x4 be1 = *(const f32x4*)(beff + gcol1);
  const f32x4 be2 = *(const f32x4*)(beff + gcol2);

  // h-stage: thread -> row srow, 8 packed cols at sc0_
  const int srow = tid >> 5, sc0_ = (tid & 31) * 8;

  __syncthreads();   // Xs staged

  // prologue: xw(0) -> xwlds[0]
  {
    f32x4 v1 = be1, v2 = be2;
    #pragma unroll
    for (int d=0; d<5; ++d){
      const int t = d - 2;
      if ((unsigned)t < 512u){
        const int ch1 = Xs[row1*512 + t] & 127;
        v1 += *(const f32x4*)(embw + (size_t)(d*128 + ch1)*768 + gcol1);
        if (two){
          const int ch2 = Xs[row2*512 + t] & 127;
          v2 += *(const f32x4*)(embw + (size_t)(d*128 + ch2)*768 + gcol2);
        }
      }
    }
    *(f32x4*)&xwlds[0][row1][gg1*64 + cc1*4] = v1;
    if (two) *(f32x4*)&xwlds[0][row2][gg2*64 + cc2*4] = v2;
  }
  float hpA = 0.f, hpB = 0.f;
  __syncthreads();

  for (int s = 0; s < 512; ++s){
    const int par = s & 1;

    // S1) spin until this thread's 8 h-words are valid (mark bit0, em).
    const u32 em = (u32)((s >> 1) & 1);
    u32* hb = hgp + (unsigned)par*32768u + (unsigned)g*4096u
              + (unsigned)srow*256u + (unsigned)sc0_;
    u32 wd[8];
    if (localg){
      // L2-local path: HW atomic-or reads (execute AT the shared L2)
      u32 z = 0u;
      int guard = 0;
      for (;;){
        u32 w0,w1,w2,w3,w4,w5,w6,w7;
        asm volatile(
          "global_atomic_or %0, %8, %9, off sc0\n\t"
          "global_atomic_or %1, %8, %9, off offset:4 sc0\n\t"
          "global_atomic_or %2, %8, %9, off offset:8 sc0\n\t"
          "global_atomic_or %3, %8, %9, off offset:12 sc0\n\t"
          "global_atomic_or %4, %8, %9, off offset:16 sc0\n\t"
          "global_atomic_or %5, %8, %9, off offset:20 sc0\n\t"
          "global_atomic_or %6, %8, %9, off offset:24 sc0\n\t"
          "global_atomic_or %7, %8, %9, off offset:28 sc0"
          : "=&v"(w0),"=&v"(w1),"=&v"(w2),"=&v"(w3),
            "=&v"(w4),"=&v"(w5),"=&v"(w6),"=&v"(w7)
          : "v"(hb), "v"(z)
          : "memory");
        asm volatile("s_waitcnt vmcnt(0)"
          : "+v"(w0),"+v"(w1),"+v"(w2),"+v"(w3),
            "+v"(w4),"+v"(w5),"+v"(w6),"+v"(w7) :: "memory");
        __builtin_amdgcn_sched_barrier(0);
        wd[0]=w0; wd[1]=w1; wd[2]=w2; wd[3]=w3;
        wd[4]=w4; wd[5]=w5; wd[6]=w6; wd[7]=w7;
        u32 ba = ~0u, bo = 0u;
        #pragma unroll
        for (int j=0; j<8; ++j){ ba &= wd[j]; bo |= wd[j]; }
        const bool ok = em ? ((ba & 1u) == 1u) : ((bo & 1u) == 0u);
        if (ok || ++guard > (1<<18)) break;
      }
    } else {
      // agent path (R14): batched asm probe, SSA-safe waitcnt
      i32x4 A, B;
      int guard = 0;
      for (;;){
        asm volatile("global_load_dwordx4 %0, %2, off sc0 sc1\n\t"
                     "global_load_dwordx4 %1, %3, off sc0 sc1"
                     : "=&v"(A), "=&v"(B)
                     : "v"((const u32*)hb), "v"((const u32*)hb + 4)
                     : "memory");
        asm volatile("s_waitcnt vmcnt(0)" : "+v"(A), "+v"(B) :: "memory");
        __builtin_amdgcn_sched_barrier(0);
        const u32 ba = (u32)A[0] & (u32)A[1] & (u32)A[2] & (u32)A[3]
                     & (u32)B[0] & (u32)B[1] & (u32)B[2] & (u32)B[3];
        const u32 bo = (u32)A[0] | (u32)A[1] | (u32)A[2] | (u32)A[3]
                     | (u32)B[0] | (u32)B[1] | (u32)B[2] | (u32)B[3];
        const bool ok = em ? ((ba & 1u) == 1u) : ((bo & 1u) == 0u);
        if (ok || ++guard > (1<<20)) break;
      }
      wd[0]=(u32)A[0]; wd[1]=(u32)A[1]; wd[2]=(u32)A[2]; wd[3]=(u32)A[3];
      wd[4]=(u32)B[0]; wd[5]=(u32)B[1]; wd[6]=(u32)B[2]; wd[7]=(u32)B[3];
    }
    // de-interleave word = (hi<<16) | lo  -> stage planes
    {
      s16x8 hi, lo;
      #pragma unroll
      for (int j=0; j<8; ++j){ hi[j] = (short)(wd[j] >> 16); lo[j] = (short)(wd[j] & 0xFFFFu); }
      *(s16x8*)&hstage[0][srow][sc0_] = hi;
      *(s16x8*)&hstage[1][srow][sc0_] = lo;
    }
    __syncthreads();                          // barA: stage ready

    // S2) partial hw over this wave's K-half: 24 MFMAs
    f32x4 a0 = {0.f,0.f,0.f,0.f}, a1 = a0, a2 = a0;
    #pragma unroll
    for (int qi=0; qi<4; ++qi){
      const int kb = (qs+qi)*32 + l4*8;
      const s16x8 ahi = *(const s16x8*)&hstage[0][l15][kb];
      const s16x8 alo = *(const s16x8*)&hstage[1][l15][kb];
      a0 = __builtin_amdgcn_mfma_f32_16x16x32_bf16(ahi, Bf[0][qi], a0, 0,0,0);
      a1 = __builtin_amdgcn_mfma_f32_16x16x32_bf16(ahi, Bf[1][qi], a1, 0,0,0);
      a2 = __builtin_amdgcn_mfma_f32_16x16x32_bf16(ahi, Bf[2][qi], a2, 0,0,0);
      a0 = __builtin_amdgcn_mfma_f32_16x16x32_bf16(alo, Bf[0][qi], a0, 0,0,0);
      a1 = __builtin_amdgcn_mfma_f32_16x16x32_bf16(alo, Bf[1][qi], a1, 0,0,0);
      a2 = __builtin_amdgcn_mfma_f32_16x16x32_bf16(alo, Bf[2][qi], a2, 0,0,0);
    }
    {
      const int kh = w >> 2, sc = (w&3)*16 + l15;
      #pragma unroll
      for (int p=0; p<4; ++p){
        hwp[kh][l4*4+p][       sc] = a0[p];
        hwp[kh][l4*4+p][ 64 + sc] = a1[p];
        hwp[kh][l4*4+p][128 + sc] = a2[p];
      }
    }

    // S3) gather xw(s+1): issue now (L2 latency hides until gates consume)
    f32x4 n1, n2;
    if (s < 511){
      n1 = be1; n2 = be2;
      #pragma unroll
      for (int d=0; d<5; ++d){
        const int t = s - 1 + d;
        if ((unsigned)t < 512u){
          const int ch1 = Xs[row1*512 + t] & 127;
          n1 += *(const f32x4*)(embw + (size_t)(d*128 + ch1)*768 + gcol1);
          if (two){
            const int ch2 = Xs[row2*512 + t] & 127;
            n2 += *(const f32x4*)(embw + (size_t)(d*128 + ch2)*768 + gcol2);
          }
        }
      }
    }
    __syncthreads();                          // barB: hwp ready

    // S4) gates for units (tr, hc) and (tr+8, hc)
    float hnA, hnB;
    #pragma unroll
    for (int u=0; u<2; ++u){
      const int row = tr + u*8;
      const float hz = hwp[0][row][      c63] + hwp[1][row][      c63] + br0;
      const float hr = hwp[0][row][ 64 + c63] + hwp[1][row][ 64 + c63] + br1;
      const float hh = hwp[0][row][128 + c63] + hwp[1][row][128 + c63] + br2;
      const float xz = xwlds[par][row][      c63];
      const float xr = xwlds[par][row][ 64 + c63];
      const float xh = xwlds[par][row][128 + c63];
      const float hp = u ? hpB : hpA;
      const float z  = 1.f/(1.f + __expf(-(xz + hz)));
      const float rg = 1.f/(1.f + __expf(-(xr + hr)));
      const float pre = xh + rg*hh;
      const float e2  = __expf(-2.f*fabsf(pre));
      const float th  = __builtin_copysignf((1.f - e2)/(1.f + e2), pre);
      const float hn  = z*hp + (1.f - z)*th;
      if (u) hnB = hn; else hnA = hn;
    }
    hpA = hnA; hpB = hnB;

    // S5) publish h(s+1) with embedded mark, or final output
    if (s == 511){
      const int i0 = (g*16 + tr)*256 + hc;
      if (md){ ((float*)outv)[i0] = hnA; ((float*)outv)[i0 + 8*256] = hnB; }
      else   { ((u16*)outv)[i0] = f2bf(hnA); ((u16*)outv)[i0 + 8*256] = f2bf(hnB); }
    } else {
      const u32 sm = (u32)(((s + 1) >> 1) & 1);
      u32* hb2 = hgp + (unsigned)(par^1)*32768u + (unsigned)g*4096u;
      #pragma unroll
      for (int u=0; u<2; ++u){
        const float hn = u ? hnB : hnA;
        const u32 bh = f2bf(hn);
        u32 bl = f2bf(hn - bf2f((u16)bh));
        bl = (bl & ~1u) | sm;                 // steal lo LSB for the step-mark
        const u32 word = (bh << 16) | bl;
        u32* dst = hb2 + (tr + u*8)*256 + hc;
        if (localg)
          atom_pub(dst, word);                 // HW swap at shared L2
        else
          __hip_atomic_store(dst, word, __ATOMIC_RELAXED, __HIP_MEMORY_SCOPE_AGENT);
      }
      // xw(s+1) -> other LDS buffer
      *(f32x4*)&xwlds[par^1][row1][gg1*64 + cc1*4] = n1;
      if (two) *(f32x4*)&xwlds[par^1][row2][gg2*64 + cc2*4] = n2;
    }
  }
}

extern "C" void kernel_launch(void* const* d_in, const int* in_sizes, int n_in,
                              void* d_out, int out_size, void* d_ws, size_t ws_size,
                              hipStream_t stream){
  const int* X = (const int*)d_in[0];
  char* ws = (char*)d_ws;
  if (ws_size < WS_NEED) return;

  k_init <<<256, 256, 0, stream>>>(ws);
  k_probe<<<  1,  64, 0, stream>>>(d_in[1], ws);
  k_wc   <<<320, 256, 0, stream>>>(d_in[2], d_in[4], d_in[6], d_in[8], d_in[10], ws);
  k_beff <<<  3, 256, 0, stream>>>(d_in[3], d_in[5], d_in[7], d_in[9], d_in[10], d_in[12], ws);
  k_embw <<<640, 256, 0, stream>>>(d_in[1], ws);
  k_whp  <<<768, 256, 0, stream>>>(d_in[11], ws);
  k_gru  <<< 32, 512, 0, stream>>>(X, d_in[13], ws, d_out);
}

// Round 17
// 3614.321 us; speedup vs baseline: 1.1488x; 1.1488x over previous
//
#include <hip/hip_runtime.h>
#include <hip/hip_bf16.h>

// ---------------------------------------------------------------------------
// CharRNN: emb -> 4x conv1d(SAME) -> concat -> GRU(256) last state.
//
// xw[b,t,:] = beff + sum_{d=0..4} EmbW[d][X[b,t+d-2]][:]   (f32 tables in ws)
//
// R17: R16 proved L2-local exchange is a dead end (atomic RMW probes = 2.8GB
// write storm; loads = stale L1). Keep R14's proven agent protocol, hide the
// latency instead: each block interleaves TWO independent recurrences
// (groups 2p and 2p+1). Phase order A(s),B(s),A(s+1)...: each stream's
// store-flight lands under the other stream's compute. 16 blocks = 4 pairs
// x 4 slices; Wh regs shared; hwp/hstage LDS time-shared (barrier-ordered);
// X read direct (L2). Plane-1 init = mark-invalid (kills step-1 init race).
// Numerics identical to R14: absmax 9.8e-4.
// ---------------------------------------------------------------------------

typedef float f32x4 __attribute__((ext_vector_type(4)));
typedef short s16x8 __attribute__((ext_vector_type(8)));
typedef int   i32x4 __attribute__((ext_vector_type(4)));
typedef unsigned short u16;
typedef unsigned int   u32;
typedef unsigned long long u64;

// ws byte offsets
#define OFF_WC    0u         // f32  [5][64][768]
#define OFF_EMBW  983040u    // f32  [5][128][768]
#define OFF_BEFF  2949120u   // f32  [768]
#define OFF_WHP   2952192u   // bf16 [768][256] (Wh^T)
#define OFF_MODE  3345408u   // int
#define OFF_HGP   3345472u   // u32 [2][8][16][256]  (par, group, row, hcol)
#define WS_NEED   3607616u

__device__ __forceinline__ float bf2f(u16 v){
  unsigned u = ((unsigned)v) << 16; return __builtin_bit_cast(float, u);
}
__device__ __forceinline__ u16 f2bf(float f){
  unsigned u = __builtin_bit_cast(unsigned, f);
  unsigned r = u + 0x7FFFu + ((u >> 16) & 1u);
  return (u16)(r >> 16);
}
__device__ __forceinline__ float ldv(const void* p, int i, int m){
  return m ? ((const float*)p)[i] : bf2f(((const u16*)p)[i]);
}

// ---- init: plane0 = 0 (valid zeros for h(0)); plane1 = 1 (mark-invalid) ----
__global__ void k_init(char* ws){
  int idx = blockIdx.x*256 + threadIdx.x;
  u32* hg = (u32*)(ws + OFF_HGP);
  if (idx < 65536) hg[idx] = (idx < 32768) ? 0u : 1u;
}

// ---- probe: detect storage dtype of emb_table ----
__global__ void k_probe(const void* __restrict__ emb, char* ws){
  const u16* w = (const u16*)emb;
  const int ln = threadIdx.x;
  bool bad = false;
  for (int j = 0; j < 8; ++j){
    u16 v = w[ln*8 + j];
    if (((v >> 7) & 0xFF) >= 0x86) bad = true;
  }
  unsigned long long m = __ballot(bad);
  if (ln == 0) *(int*)(ws + OFF_MODE) = (__popcll(m) > 4) ? 1 : 0;
}

// ---- Wc[d][e][j] = sum_br sum_c w_br[d-2+pad][e][c] * Wx[off_br+c][j] ----
__global__ void k_wc(const void* __restrict__ w2, const void* __restrict__ w3,
                     const void* __restrict__ w4, const void* __restrict__ w5,
                     const void* __restrict__ Wx, char* ws){
  const int md = *(const int*)(ws + OFF_MODE);
  const int d = blockIdx.x >> 6;
  const int e = blockIdx.x & 63;
  const int j0 = threadIdx.x;
  const void* wv[4] = {w2,w3,w4,w5};
  const int Kk[4] = {2,3,4,5}, pd[4] = {0,1,1,2};
  float a0=0.f, a1=0.f, a2=0.f;
  for (int br=0; br<4; ++br){
    int k = d - 2 + pd[br];
    if (k < 0 || k >= Kk[br]) continue;
    const int wbase  = (k*64 + e)*128;
    const int wxbase = (br*128)*768;
    for (int c=0; c<128; ++c){
      float wcv = ldv(wv[br], wbase + c, md);
      a0 += wcv * ldv(Wx, wxbase + c*768 + j0      , md);
      a1 += wcv * ldv(Wx, wxbase + c*768 + j0 + 256, md);
      a2 += wcv * ldv(Wx, wxbase + c*768 + j0 + 512, md);
    }
  }
  float* o = (float*)(ws + OFF_WC) + (d*64 + e)*768;
  o[j0] = a0; o[j0+256] = a1; o[j0+512] = a2;
}

// ---- beff[j] = b_in[j] + sum_br sum_c b_br[c]*Wx[off+c][j] ----
__global__ void k_beff(const void* __restrict__ b2, const void* __restrict__ b3,
                       const void* __restrict__ b4, const void* __restrict__ b5,
                       const void* __restrict__ Wx, const void* __restrict__ bin,
                       char* ws){
  const int md = *(const int*)(ws + OFF_MODE);
  int j = blockIdx.x*256 + threadIdx.x;
  if (j >= 768) return;
  const void* bv[4] = {b2,b3,b4,b5};
  float acc = ldv(bin, j, md);
  for (int br=0; br<4; ++br)
    for (int c=0; c<128; ++c)
      acc += ldv(bv[br], c, md) * ldv(Wx, (br*128 + c)*768 + j, md);
  ((float*)(ws + OFF_BEFF))[j] = acc;
}

// ---- EmbW[d][ch][j] = sum_e emb[ch][e] * Wc[d][e][j]  (f32 out) ----
__global__ void k_embw(const void* __restrict__ emb, char* ws){
  const int md = *(const int*)(ws + OFF_MODE);
  const int d = blockIdx.x >> 7, ch = blockIdx.x & 127;
  const float* wc = (const float*)(ws + OFF_WC) + d*64*768;
  float* ew = (float*)(ws + OFF_EMBW) + (size_t)(d*128 + ch)*768;
  const int j0 = threadIdx.x;
  float a0=0.f, a1=0.f, a2=0.f;
  for (int e=0; e<64; ++e){
    float ev = ldv(emb, ch*64 + e, md);
    a0 += ev*wc[e*768 + j0      ];
    a1 += ev*wc[e*768 + j0 + 256];
    a2 += ev*wc[e*768 + j0 + 512];
  }
  ew[j0] = a0; ew[j0+256] = a1; ew[j0+512] = a2;
}

// ---- whp[j][k] = Wh[k][j]  (bf16 out) ----
__global__ void k_whp(const void* __restrict__ Wh, char* ws){
  const int md = *(const int*)(ws + OFF_MODE);
  const int j = blockIdx.x, k = threadIdx.x;
  ((u16*)(ws + OFF_WHP))[j*256 + k] = f2bf(ldv(Wh, k*768 + j, md));
}

// ---- GRU: 16 blocks = 4 group-pairs x 4 slices; 512 thr / 8 waves ----
__launch_bounds__(512, 1)
__global__ void k_gru(const int* __restrict__ X, const void* __restrict__ brec,
                      char* __restrict__ ws, void* __restrict__ outv){
  const int tid = threadIdx.x;
  const int w   = tid >> 6, ln = tid & 63;
  const int l15 = ln & 15, l4 = ln >> 4;
  const int pr = blockIdx.x >> 2, r = blockIdx.x & 3;
  const int g0 = pr*2;                    // streams: groups g0, g0+1

  const int md = *(const int*)(ws + OFF_MODE);
  const float* embw = (const float*)(ws + OFF_EMBW);
  const float* beff = (const float*)(ws + OFF_BEFF);
  const u16*   whp  = (const u16*)(ws + OFF_WHP);
  u32* hgp = (u32*)(ws + OFF_HGP);

  __shared__ float xwlds[2][2][16][196];   // [stream][par][row][col]  50 KB
  __shared__ float hwp[2][16][196];        // time-shared across phases 25 KB
  __shared__ u16   hstage[2][16][272];     // time-shared               17 KB

  // persistent Wh B-frags: wave w -> subtile w&3, K-half w>>2 (stream-invariant)
  const int qs = (w >> 2) * 4;
  s16x8 Bf[3][4];
  #pragma unroll
  for (int gg=0; gg<3; ++gg){
    const int col = gg*256 + r*64 + (w&3)*16 + l15;
    #pragma unroll
    for (int qi=0; qi<4; ++qi)
      Bf[gg][qi] = *(const s16x8*)(whp + col*256 + (qs+qi)*32 + l4*8);
  }

  // gates: thread -> h-col hc = r*64+(tid&63), rows tr, tr+8
  const int c63 = tid & 63;
  const int tr  = (tid >> 6) & 7;
  const int hc  = r*64 + c63;
  const float br0 = ldv(brec,       hc, md);
  const float br1 = ldv(brec, 256 + hc, md);
  const float br2 = ldv(brec, 512 + hc, md);

  // gather: chunk ids cid1 = tid, cid2 = tid+512 (tid<256 only)
  const int row1 = tid / 48,      rem1 = tid % 48;
  const int gg1  = rem1 / 16,     cc1  = rem1 % 16;
  const int cid2 = tid + 512;
  const int row2 = cid2 / 48,     rem2 = cid2 % 48;
  const int gg2  = rem2 / 16,     cc2  = rem2 % 16;
  const bool two = (tid < 256);
  const int gcol1 = gg1*256 + r*64 + cc1*4;
  const int gcol2 = gg2*256 + r*64 + cc2*4;
  const int o1 = gg1*64 + cc1*4, o2 = gg2*64 + cc2*4;
  const f32x4 be1 = *(const f32x4*)(beff + gcol1);
  const f32x4 be2 = *(const f32x4*)(beff + gcol2);

  // h-stage: thread -> row srow, 8 packed cols at sc0_
  const int srow = tid >> 5, sc0_ = (tid & 31) * 8;

  // prologue: xw(0) for both streams (X direct from global; L2-hot)
  #pragma unroll
  for (int st=0; st<2; ++st){
    const int g = g0 + st;
    f32x4 v1 = be1, v2 = be2;
    #pragma unroll
    for (int d=0; d<5; ++d){
      const int t = d - 2;
      if ((unsigned)t < 512u){
        const int ch1 = X[(g*16 + row1)*512 + t] & 127;
        v1 += *(const f32x4*)(embw + (size_t)(d*128 + ch1)*768 + gcol1);
        if (two){
          const int ch2 = X[(g*16 + row2)*512 + t] & 127;
          v2 += *(const f32x4*)(embw + (size_t)(d*128 + ch2)*768 + gcol2);
        }
      }
    }
    *(f32x4*)&xwlds[st][0][row1][o1] = v1;
    if (two) *(f32x4*)&xwlds[st][0][row2][o2] = v2;
  }
  float hp[2][2] = {{0.f,0.f},{0.f,0.f}};
  __syncthreads();

  for (int s = 0; s < 512; ++s){
    const int par = s & 1;
    const u32 em = (u32)((s >> 1) & 1);
    const u32 sm = (u32)(((s + 1) >> 1) & 1);

    #pragma unroll
    for (int st=0; st<2; ++st){
      const int g = g0 + st;

      // S1) probe this thread's 8 h-words (R14 batched asm, SSA-safe)
      u32* hb = hgp + (unsigned)par*32768u + (unsigned)g*4096u
                + (unsigned)srow*256u + (unsigned)sc0_;
      i32x4 A, B;
      {
        int guard = 0;
        for (;;){
          asm volatile("global_load_dwordx4 %0, %2, off sc0 sc1\n\t"
                       "global_load_dwordx4 %1, %3, off sc0 sc1"
                       : "=&v"(A), "=&v"(B)
                       : "v"((const u32*)hb), "v"((const u32*)hb + 4)
                       : "memory");
          asm volatile("s_waitcnt vmcnt(0)" : "+v"(A), "+v"(B) :: "memory");
          __builtin_amdgcn_sched_barrier(0);
          const u32 ba = (u32)A[0] & (u32)A[1] & (u32)A[2] & (u32)A[3]
                       & (u32)B[0] & (u32)B[1] & (u32)B[2] & (u32)B[3];
          const u32 bo = (u32)A[0] | (u32)A[1] | (u32)A[2] | (u32)A[3]
                       | (u32)B[0] | (u32)B[1] | (u32)B[2] | (u32)B[3];
          const bool ok = em ? ((ba & 1u) == 1u) : ((bo & 1u) == 0u);
          if (ok || ++guard > (1<<16)) break;   // fail visibly, no timeout
        }
      }
      {
        u32 wd[8] = {(u32)A[0],(u32)A[1],(u32)A[2],(u32)A[3],
                     (u32)B[0],(u32)B[1],(u32)B[2],(u32)B[3]};
        s16x8 hi, lo;
        #pragma unroll
        for (int j=0; j<8; ++j){ hi[j] = (short)(wd[j] >> 16); lo[j] = (short)(wd[j] & 0xFFFFu); }
        *(s16x8*)&hstage[0][srow][sc0_] = hi;
        *(s16x8*)&hstage[1][srow][sc0_] = lo;
      }
      __syncthreads();                          // barA: stage ready

      // S2) partial hw over this wave's K-half: 24 MFMAs
      f32x4 a0 = {0.f,0.f,0.f,0.f}, a1 = a0, a2 = a0;
      #pragma unroll
      for (int qi=0; qi<4; ++qi){
        const int kb = (qs+qi)*32 + l4*8;
        const s16x8 ahi = *(const s16x8*)&hstage[0][l15][kb];
        const s16x8 alo = *(const s16x8*)&hstage[1][l15][kb];
        a0 = __builtin_amdgcn_mfma_f32_16x16x32_bf16(ahi, Bf[0][qi], a0, 0,0,0);
        a1 = __builtin_amdgcn_mfma_f32_16x16x32_bf16(ahi, Bf[1][qi], a1, 0,0,0);
        a2 = __builtin_amdgcn_mfma_f32_16x16x32_bf16(ahi, Bf[2][qi], a2, 0,0,0);
        a0 = __builtin_amdgcn_mfma_f32_16x16x32_bf16(alo, Bf[0][qi], a0, 0,0,0);
        a1 = __builtin_amdgcn_mfma_f32_16x16x32_bf16(alo, Bf[1][qi], a1, 0,0,0);
        a2 = __builtin_amdgcn_mfma_f32_16x16x32_bf16(alo, Bf[2][qi], a2, 0,0,0);
      }
      {
        const int kh = w >> 2, sc = (w&3)*16 + l15;
        #pragma unroll
        for (int p=0; p<4; ++p){
          hwp[kh][l4*4+p][       sc] = a0[p];
          hwp[kh][l4*4+p][ 64 + sc] = a1[p];
          hwp[kh][l4*4+p][128 + sc] = a2[p];
        }
      }

      // S3) gather xw(s+1) for this stream (X direct; L2 latency hides)
      f32x4 n1, n2;
      if (s < 511){
        n1 = be1; n2 = be2;
        #pragma unroll
        for (int d=0; d<5; ++d){
          const int t = s - 1 + d;
          if ((unsigned)t < 512u){
            const int ch1 = X[(g*16 + row1)*512 + t] & 127;
            n1 += *(const f32x4*)(embw + (size_t)(d*128 + ch1)*768 + gcol1);
            if (two){
              const int ch2 = X[(g*16 + row2)*512 + t] & 127;
              n2 += *(const f32x4*)(embw + (size_t)(d*128 + ch2)*768 + gcol2);
            }
          }
        }
      }
      __syncthreads();                          // barB: hwp ready

      // S4) gates for units (tr, hc) and (tr+8, hc)
      float hnA, hnB;
      #pragma unroll
      for (int u=0; u<2; ++u){
        const int row = tr + u*8;
        const float hz = hwp[0][row][      c63] + hwp[1][row][      c63] + br0;
        const float hr = hwp[0][row][ 64 + c63] + hwp[1][row][ 64 + c63] + br1;
        const float hh = hwp[0][row][128 + c63] + hwp[1][row][128 + c63] + br2;
        const float xz = xwlds[st][par][row][      c63];
        const float xr = xwlds[st][par][row][ 64 + c63];
        const float xh = xwlds[st][par][row][128 + c63];
        const float hpv = hp[st][u];
        const float z  = 1.f/(1.f + __expf(-(xz + hz)));
        const float rg = 1.f/(1.f + __expf(-(xr + hr)));
        const float pre = xh + rg*hh;
        const float e2  = __expf(-2.f*fabsf(pre));
        const float th  = __builtin_copysignf((1.f - e2)/(1.f + e2), pre);
        const float hn  = z*hpv + (1.f - z)*th;
        if (u) hnB = hn; else hnA = hn;
      }
      hp[st][0] = hnA; hp[st][1] = hnB;

      // S5) publish h(s+1) with embedded mark, or final output
      if (s == 511){
        const int i0 = (g*16 + tr)*256 + hc;
        if (md){ ((float*)outv)[i0] = hnA; ((float*)outv)[i0 + 8*256] = hnB; }
        else   { ((u16*)outv)[i0] = f2bf(hnA); ((u16*)outv)[i0 + 8*256] = f2bf(hnB); }
      } else {
        u32* hb2 = hgp + (unsigned)(par^1)*32768u + (unsigned)g*4096u;
        #pragma unroll
        for (int u=0; u<2; ++u){
          const float hn = u ? hnB : hnA;
          const u32 bh = f2bf(hn);
          u32 bl = f2bf(hn - bf2f((u16)bh));
          bl = (bl & ~1u) | sm;                 // steal lo LSB for the step-mark
          __hip_atomic_store(hb2 + (tr + u*8)*256 + hc, (bh << 16) | bl,
                             __ATOMIC_RELAXED, __HIP_MEMORY_SCOPE_AGENT);
        }
        // xw(s+1) -> other parity buffer of this stream
        *(f32x4*)&xwlds[st][par^1][row1][o1] = n1;
        if (two) *(f32x4*)&xwlds[st][par^1][row2][o2] = n2;
      }
    }
  }
}

extern "C" void kernel_launch(void* const* d_in, const int* in_sizes, int n_in,
                              void* d_out, int out_size, void* d_ws, size_t ws_size,
                              hipStream_t stream){
  const int* X = (const int*)d_in[0];
  char* ws = (char*)d_ws;
  if (ws_size < WS_NEED) return;

  k_init <<<256, 256, 0, stream>>>(ws);
  k_probe<<<  1,  64, 0, stream>>>(d_in[1], ws);
  k_wc   <<<320, 256, 0, stream>>>(d_in[2], d_in[4], d_in[6], d_in[8], d_in[10], ws);
  k_beff <<<  3, 256, 0, stream>>>(d_in[3], d_in[5], d_in[7], d_in[9], d_in[10], d_in[12], ws);
  k_embw <<<640, 256, 0, stream>>>(d_in[1], ws);
  k_whp  <<<768, 256, 0, stream>>>(d_in[11], ws);
  k_gru  <<< 16, 512, 0, stream>>>(X, d_in[13], ws, d_out);
}